// Round 1
// baseline (122.610 us; speedup 1.0000x reference)
//
#include <hip/hip_runtime.h>

#define NB_MAX 8192
#define NTHR 256

// scalars: [0]=P  [8]=g0 [9]=g1 [10]=g2 [11]=g1*g2 [12]=nb  [13]=doneA
// Cross-block sync rules learned on this chip (earlier rounds):
//   grid.sync ~45us; global spin-barriers >100us; per-thread agent FENCES ~60us/kernel.
//   Cheap patterns: relaxed agent atomics (coherent, no fence) — used for
//   last-finishing-block (K1) and decoupled lookback (K2, value+flag packed in
//   one 64-bit word so a single relaxed atomic load is self-consistent).

// K1: per-atom frac/pv/histogram; LAST-FINISHING block scans buckets -> cumc/pairoff/P.
__global__ __launch_bounds__(NTHR) void k_count(
    const float* __restrict__ coord,
    const float* __restrict__ cell,
    float* __restrict__ out_frac,
    int* __restrict__ pv,
    int* __restrict__ counts,
    int* __restrict__ scalars,
    int* __restrict__ cumc,
    int* __restrict__ pairoff,
    int n) {
  __shared__ int shA[4], shB[4];
  __shared__ int isLast;
  int t = threadIdx.x;
  int lane = t & 63, wid = t >> 6;
  int a = blockIdx.x * NTHR + t;

  float d0 = cell[0], d1 = cell[4], d2 = cell[8];
  const float bl = (float)(5.2 + 1e-05);
  int g0 = (int)floorf(d0 / bl) + 1;
  int g1 = (int)floorf(d1 / bl) + 1;
  int g2 = (int)floorf(d2 / bl) + 1;
  int g12 = g1 * g2;
  if (a == 0) {
    scalars[8] = g0; scalars[9] = g1; scalars[10] = g2;
    scalars[11] = g12; scalars[12] = g0 * g12;
  }
  if (a < n) {
    float x = coord[3 * a + 0], y = coord[3 * a + 1], z = coord[3 * a + 2];
    float fx = x / d0, fy = y / d1, fz = z / d2;
    out_frac[3 * a + 0] = fx;
    out_frac[3 * a + 1] = fy;
    out_frac[3 * a + 2] = fz;
    int v0 = (int)rintf(fx * (float)(g0 - 1));
    int v1 = (int)rintf(fy * (float)(g1 - 1));
    int v2 = (int)rintf(fz * (float)(g2 - 1));
    pv[a] = (v0 << 20) | (v1 << 10) | v2;
    atomicAdd(&counts[v0 * g12 + v1 * g1 + v2], 1);  // device-scope, coherent point
  }

  // __syncthreads drains vmcnt -> this block's atomics are performed before t0's add.
  __syncthreads();
  if (t == 0) {
    int old = __hip_atomic_fetch_add(&scalars[13], 1, __ATOMIC_RELAXED,
                                     __HIP_MEMORY_SCOPE_AGENT);
    isLast = (old == (int)gridDim.x - 1) ? 1 : 0;
  }
  __syncthreads();
  if (!isLast) return;

  // bucket scan (256 thr x 32); counts via relaxed agent atomic loads (coherent reads)
  int nb = g0 * g12;
  const int IT = NB_MAX / NTHR;  // 32
  int base2 = t * IT;
  int cv[IT];
  int lc = 0, lp = 0;
#pragma unroll
  for (int i = 0; i < IT; ++i) {
    int idx = base2 + i;
    int c = (idx < nb)
        ? __hip_atomic_load(&counts[idx], __ATOMIC_RELAXED, __HIP_MEMORY_SCOPE_AGENT)
        : 0;
    cv[i] = c;
    lc += c;
    lp += c * (c - 1) / 2;
  }
  int ic = lc, ip = lp;
  for (int off = 1; off < 64; off <<= 1) {
    int yc = __shfl_up(ic, off);
    int yp = __shfl_up(ip, off);
    if (lane >= off) { ic += yc; ip += yp; }
  }
  if (lane == 63) { shA[wid] = ic; shB[wid] = ip; }
  __syncthreads();
  if (wid == 0 && lane < 4) {
    int vc2 = shA[lane], vp2 = shB[lane];
    int sc2 = vc2, sp2 = vp2;
    for (int off = 1; off < 4; off <<= 1) {
      int yc = __shfl_up(sc2, off);
      int yp = __shfl_up(sp2, off);
      if (lane >= off) { sc2 += yc; sp2 += yp; }
    }
    shA[lane] = sc2 - vc2;
    shB[lane] = sp2 - vp2;
  }
  __syncthreads();
  int ec = shA[wid] + (ic - lc);
  int ep = shB[wid] + (ip - lp);
#pragma unroll
  for (int i = 0; i < IT; ++i) {
    int idx = base2 + i;
    if (idx < nb) { cumc[idx] = ec; pairoff[idx] = ep; }
    ec += cv[i];
    ep += cv[i] * (cv[i] - 1) / 2;
  }
  if (t == NTHR - 1) scalars[0] = ep;  // total P (plain store; next kernel sees it)
}

// K2: scatter + per-atom neighbor segments + block scan + DECOUPLED LOOKBACK
//     (relaxed agent atomics, value|flag packed in 64-bit, no fences) + emit.
//     Emit no longer waits for a kernel boundary: a block emits as soon as its
//     exclusive prefix resolves (~wavefront of 64 blocks per L2 round trip).
__global__ __launch_bounds__(NTHR) void k_scatter_emit(
    const int* __restrict__ pv,
    const int* __restrict__ cumc,
    const int* __restrict__ counts,
    const int* __restrict__ scalars,
    int* __restrict__ fill,
    int* __restrict__ sorted,
    unsigned long long* __restrict__ lookback,
    float* __restrict__ out,
    int n) {
  __shared__ int shA[4];
  __shared__ int Lsegs[NTHR][7];  // inclusive segment ends per atom (segs[1..7])
  __shared__ int Lcums[NTHR][7];  // neighbor-bucket cumc per atom
  __shared__ int Lexcl[NTHR];     // block-local exclusive S-prefix per atom
  __shared__ int sh_agg, sh_E;
  int t = threadIdx.x;
  int lane = t & 63, wid = t >> 6;
  int bid = blockIdx.x;
  int a = bid * NTHR + t;
  int g0 = scalars[8], g1 = scalars[9], g2 = scalars[10], g12 = scalars[11];

  int S = 0;
  if (a < n) {
    int p = pv[a];
    int v0 = p >> 20, v1 = (p >> 10) & 1023, v2 = p & 1023;
    int b = v0 * g12 + v1 * g1 + v2;
    int pos = cumc[b] + atomicAdd(&fill[b], 1);
    sorted[pos] = a;  // plain store; read after next kernel boundary (coherent then)
    int seg = 0;
#pragma unroll
    for (int m = 0; m < 7; ++m) {
      int dx = ((m >> 2) & 1) ? 0 : -1;
      int dy = ((m >> 1) & 1) ? 0 : -1;
      int dz = (m & 1) ? 0 : -1;
      int nx = v0 + dx; if (nx < 0) nx += g0;
      int ny = v1 + dy; if (ny < 0) ny += g1;
      int nz = v2 + dz; if (nz < 0) nz += g2;
      int nb_ = nx * g12 + ny * g1 + nz;
      Lcums[t][m] = cumc[nb_];
      seg += counts[nb_];
      Lsegs[t][m] = seg;
    }
    S = seg;
  } else {
#pragma unroll
    for (int m = 0; m < 7; ++m) { Lsegs[t][m] = 0; Lcums[t][m] = 0; }
  }

  // block scan of S -> per-atom exclusive offset + block aggregate
  int iv = S;
  for (int off = 1; off < 64; off <<= 1) {
    int y = __shfl_up(iv, off);
    if (lane >= off) iv += y;
  }
  if (lane == 63) shA[wid] = iv;
  __syncthreads();
  if (wid == 0 && lane < 4) {
    int v2_ = shA[lane], s2 = v2_;
    for (int off = 1; off < 4; off <<= 1) {
      int y = __shfl_up(s2, off);
      if (lane >= off) s2 += y;
    }
    shA[lane] = s2 - v2_;
  }
  __syncthreads();
  int eoff = shA[wid] + (iv - S);
  Lexcl[t] = eoff;
  if (t == NTHR - 1) sh_agg = eoff + S;  // block total
  __syncthreads();

  // decoupled lookback on wave 0; other waves park at the barrier below
  if (wid == 0) {
    unsigned long long agg = (unsigned long long)(unsigned)sh_agg;
    if (lane == 0) {
      unsigned long long w = (agg << 32) | (bid == 0 ? 2ull : 1ull);
      __hip_atomic_store(&lookback[bid], w, __ATOMIC_RELAXED,
                         __HIP_MEMORY_SCOPE_AGENT);
    }
    asm volatile("" ::: "memory");  // keep aggregate-publish ahead of the polling
    int E = 0;
    if (bid > 0) {
      int startp = bid - 1;
      for (;;) {
        int p = startp - lane;  // lane 0 watches immediate predecessor
        unsigned long long u = (2ull);  // virtual inclusive 0 beyond block 0
        int flag = 2;
        if (p >= 0) {
          do {
            u = __hip_atomic_load(&lookback[p], __ATOMIC_RELAXED,
                                  __HIP_MEMORY_SCOPE_AGENT);
            flag = (int)(u & 3ull);
          } while (flag == 0);
        }
        int val = (int)(u >> 32);
        unsigned long long m2 = __ballot(flag == 2);
        if (m2 != 0ull) {
          int d = __ffsll((long long)m2) - 1;  // nearest inclusive prefix
          int contrib = (lane <= d) ? val : 0; // aggregates before it + it
          for (int off = 1; off < 64; off <<= 1) contrib += __shfl_xor(contrib, off);
          E += contrib;
          break;
        } else {
          int contrib = val;  // all 64 are aggregates; keep walking back
          for (int off = 1; off < 64; off <<= 1) contrib += __shfl_xor(contrib, off);
          E += contrib;
          startp -= 64;
        }
      }
      asm volatile("" ::: "memory");
      if (lane == 0) {
        unsigned long long w =
            (((unsigned long long)(unsigned)(E + sh_agg)) << 32) | 2ull;
        __hip_atomic_store(&lookback[bid], w, __ATOMIC_RELAXED,
                           __HIP_MEMORY_SCOPE_AGENT);
      }
    }
    if (lane == 0) sh_E = E;
  }
  __syncthreads();

  // emit lower_between directly: 16 lanes/atom, 16 atoms/pass, 16 passes
  int E = sh_E;
  long obase = 2L * (long)scalars[0] + (long)E;
  int l16 = t & 15;
  int sub = t >> 4;  // 0..15
#pragma unroll 1
  for (int pass = 0; pass < 16; ++pass) {
    int ai = pass * 16 + sub;
    int s1 = Lsegs[ai][0], s2 = Lsegs[ai][1], s3 = Lsegs[ai][2], s4 = Lsegs[ai][3];
    int s5 = Lsegs[ai][4], s6 = Lsegs[ai][5], s7 = Lsegs[ai][6];
    int c0 = Lcums[ai][0], c1 = Lcums[ai][1], c2 = Lcums[ai][2], c3 = Lcums[ai][3];
    int c4 = Lcums[ai][4], c5 = Lcums[ai][5], c6 = Lcums[ai][6];
    long base = obase + (long)Lexcl[ai];
    for (int q = l16; q < s7; q += 16) {
      int v = c0 + q;
      if (q >= s1) v = c1 + (q - s1);
      if (q >= s2) v = c2 + (q - s2);
      if (q >= s3) v = c3 + (q - s3);
      if (q >= s4) v = c4 + (q - s4);
      if (q >= s5) v = c5 + (q - s5);
      if (q >= s6) v = c6 + (q - s6);
      out[base + q] = (float)v;
    }
  }
}

// K3: per-bucket sort / permutation outputs / within-image pairs only.
__global__ __launch_bounds__(NTHR) void k_sort(
    const int* __restrict__ counts,
    const int* __restrict__ cumc,
    const int* __restrict__ pairoff,
    const int* __restrict__ scalars,
    int* __restrict__ sorted,
    float* __restrict__ out_im,
    float* __restrict__ out_at,
    float* __restrict__ out) {
  int t = threadIdx.x;
  int lane = t & 63, wid = t >> 6;

  int b = blockIdx.x * 4 + wid;
  int nb = scalars[12];
  if (b >= nb) return;
  int c = counts[b];
  if (c == 0) return;
  int s = cumc[b];
  if (c == 1) {
    if (lane == 0) {
      int aa = sorted[s];
      out_im[s] = (float)aa;
      out_at[aa] = (float)s;
    }
    return;
  }
  if (c <= 64) {
    int val = (lane < c) ? sorted[s + lane] : 0x7fffffff;
    int rank = 0;
    for (int j = 0; j < c; ++j) {
      int other = __shfl(val, j);
      rank += (other < val) ? 1 : 0;
    }
    if (lane < c) {
      sorted[s + rank] = val;
      out_im[s + rank] = (float)val;
      out_at[val] = (float)(s + rank);
    }
  } else if (lane == 0) {
    for (int i = 1; i < c; ++i) {
      int key = sorted[s + i];
      int j = i - 1;
      while (j >= 0 && sorted[s + j] > key) {
        sorted[s + j + 1] = sorted[s + j];
        --j;
      }
      sorted[s + j + 1] = key;
    }
    for (int i = 0; i < c; ++i) {
      int aa = sorted[s + i];
      out_im[s + i] = (float)aa;
      out_at[aa] = (float)(s + i);
    }
  }
  int off = pairoff[b];
  int P = scalars[0];
  int np = c * (c - 1) / 2;
  for (int k = lane; k < np; k += 64) {
    int l = (int)((1.0f + sqrtf(1.0f + 8.0f * (float)k)) * 0.5f);
    while (l * (l - 1) / 2 > k) --l;
    while ((l + 1) * l / 2 <= k) ++l;
    int u = k - l * (l - 1) / 2;
    out[off + k] = (float)(s + u);
    out[P + off + k] = (float)(s + l);
  }
}

extern "C" void kernel_launch(void* const* d_in, const int* in_sizes, int n_in,
                              void* d_out, int out_size, void* d_ws, size_t ws_size,
                              hipStream_t stream) {
  const float* coord = (const float*)d_in[0];
  const float* cell = (const float*)d_in[1];
  float* out = (float*)d_out;
  int n = in_sizes[0] / 3;

  int* W = (int*)d_ws;
  int* counts = W;                                   // NB_MAX
  int* fill = W + NB_MAX;                            // NB_MAX
  int* scalars = W + 2 * NB_MAX;                     // 16 (zeroed)
  unsigned long long* lookback =
      (unsigned long long*)(W + 2 * NB_MAX + 16);    // 512 x u64 (zeroed)
  int* cumc = W + 2 * NB_MAX + 16 + 1024;            // NB_MAX
  int* pairoff = cumc + NB_MAX;                      // NB_MAX
  int* pv = pairoff + NB_MAX;                        // n
  int* sorted = pv + n;                              // n

  // output chunk bases known on host: out = [2P | L | 3n | n | n]
  float* out_frac = out + (out_size - 5 * n);
  float* out_im = out + (out_size - 2 * n);
  float* out_at = out + (out_size - n);

  int nblocks = (n + NTHR - 1) / NTHR;  // 391 (<= 512 lookback slots)

  hipMemsetAsync(d_ws, 0, (size_t)(2 * NB_MAX + 16 + 1024) * sizeof(int), stream);

  k_count<<<nblocks, NTHR, 0, stream>>>(coord, cell, out_frac, pv, counts, scalars,
                                        cumc, pairoff, n);
  k_scatter_emit<<<nblocks, NTHR, 0, stream>>>(pv, cumc, counts, scalars, fill,
                                               sorted, lookback, out, n);
  k_sort<<<2048, NTHR, 0, stream>>>(counts, cumc, pairoff, scalars, sorted,
                                    out_im, out_at, out);
}

// Round 2
// 113.396 us; speedup vs baseline: 1.0813x; 1.0813x over previous
//
#include <hip/hip_runtime.h>

#define NB_MAX 8192
#define NTHR 256
#define ZBLK 32
#define ZMAGIC 0x5A17C0DE

// scalars: [0]=P  [8]=g0 [9]=g1 [10]=g2 [11]=g1*g2 [12]=nb  [13]=doneA [14]=doneB
// Cross-block sync facts measured on this chip (rounds 7-9 + round 1 of this session):
//   grid.sync ~45us; full spin-barriers >100us; per-thread agent fences ~60us/kernel;
//   decoupled-lookback chain ~= kernel boundary + ~6us (round 1: 122.6 vs 116.9).
//   Cheap patterns: relaxed agent atomics + last-finishing-block (no waiting), and
//   a SHORT bounded wait on a few immediately-starting producer blocks (used here
//   to self-zero the workspace and delete the memset dispatch: 4 -> 3 dispatches).

// K1: blocks [0,32) zero counts/fill/scalars via agent atomics then publish zf;
//     all blocks overlap coord math with that, poll zf once, then histogram.
//     LAST-FINISHING block scans buckets -> cumc/pairoff/P.
__global__ __launch_bounds__(NTHR) void k_count(
    const float* __restrict__ coord,
    const float* __restrict__ cell,
    float* __restrict__ out_frac,
    int* __restrict__ pv,
    int* __restrict__ counts,
    int* __restrict__ fill,
    int* __restrict__ scalars,
    int* __restrict__ zf,
    int* __restrict__ cumc,
    int* __restrict__ pairoff,
    int n) {
  __shared__ int shA[4], shB[4];
  __shared__ int isLast;
  int t = threadIdx.x;
  int lane = t & 63, wid = t >> 6;
  int bid = blockIdx.x;
  int a = bid * NTHR + t;

  // ---- zero phase (replaces the hipMemsetAsync dispatch) ----
  if (bid < ZBLK) {
    // agent atomics -> coherence point, so other blocks' atomicAdds can't see stale
    __hip_atomic_store(&counts[bid * NTHR + t], 0, __ATOMIC_RELAXED,
                       __HIP_MEMORY_SCOPE_AGENT);
    __hip_atomic_store(&fill[bid * NTHR + t], 0, __ATOMIC_RELAXED,
                       __HIP_MEMORY_SCOPE_AGENT);
    if (bid == 0 && t < 16)
      __hip_atomic_store(&scalars[t], 0, __ATOMIC_RELAXED,
                         __HIP_MEMORY_SCOPE_AGENT);
    // syncthreads drains vmcnt -> zero-stores performed before flag publish
    __syncthreads();
    if (t == 0)
      __hip_atomic_store(&zf[bid], ZMAGIC, __ATOMIC_RELAXED,
                         __HIP_MEMORY_SCOPE_AGENT);
  }

  // ---- per-atom work (overlaps the zero-phase wait) ----
  float d0 = cell[0], d1 = cell[4], d2 = cell[8];
  const float bl = (float)(5.2 + 1e-05);
  int g0 = (int)floorf(d0 / bl) + 1;
  int g1 = (int)floorf(d1 / bl) + 1;
  int g2 = (int)floorf(d2 / bl) + 1;
  int g12 = g1 * g2;
  if (a == 0) {
    scalars[8] = g0; scalars[9] = g1; scalars[10] = g2;
    scalars[11] = g12; scalars[12] = g0 * g12;
  }
  int bidx = 0;
  if (a < n) {
    float x = coord[3 * a + 0], y = coord[3 * a + 1], z = coord[3 * a + 2];
    float fx = x / d0, fy = y / d1, fz = z / d2;
    out_frac[3 * a + 0] = fx;
    out_frac[3 * a + 1] = fy;
    out_frac[3 * a + 2] = fz;
    int v0 = (int)rintf(fx * (float)(g0 - 1));
    int v1 = (int)rintf(fy * (float)(g1 - 1));
    int v2 = (int)rintf(fz * (float)(g2 - 1));
    pv[a] = (v0 << 20) | (v1 << 10) | v2;
    bidx = v0 * g12 + v1 * g1 + v2;
  }

  // bounded wait: 32 producer blocks start immediately; expected ~1-2 polls
  for (;;) {
    int f = (lane < ZBLK)
        ? __hip_atomic_load(&zf[lane], __ATOMIC_RELAXED, __HIP_MEMORY_SCOPE_AGENT)
        : ZMAGIC;
    if (__all(f == ZMAGIC)) break;
  }
  if (a < n) atomicAdd(&counts[bidx], 1);  // device-scope, coherent point

  // __syncthreads drains vmcnt -> this block's atomics are performed before t0's add.
  __syncthreads();
  if (t == 0) {
    int old = __hip_atomic_fetch_add(&scalars[13], 1, __ATOMIC_RELAXED,
                                     __HIP_MEMORY_SCOPE_AGENT);
    isLast = (old == (int)gridDim.x - 1) ? 1 : 0;
  }
  __syncthreads();
  if (!isLast) return;

  // bucket scan (256 thr x 32); counts via relaxed agent atomic loads (coherent reads)
  int nb = g0 * g12;
  const int IT = NB_MAX / NTHR;  // 32
  int base2 = t * IT;
  int cv[IT];
  int lc = 0, lp = 0;
#pragma unroll
  for (int i = 0; i < IT; ++i) {
    int idx = base2 + i;
    int c = (idx < nb)
        ? __hip_atomic_load(&counts[idx], __ATOMIC_RELAXED, __HIP_MEMORY_SCOPE_AGENT)
        : 0;
    cv[i] = c;
    lc += c;
    lp += c * (c - 1) / 2;
  }
  int ic = lc, ip = lp;
  for (int off = 1; off < 64; off <<= 1) {
    int yc = __shfl_up(ic, off);
    int yp = __shfl_up(ip, off);
    if (lane >= off) { ic += yc; ip += yp; }
  }
  if (lane == 63) { shA[wid] = ic; shB[wid] = ip; }
  __syncthreads();
  if (wid == 0 && lane < 4) {
    int vc2 = shA[lane], vp2 = shB[lane];
    int sc2 = vc2, sp2 = vp2;
    for (int off = 1; off < 4; off <<= 1) {
      int yc = __shfl_up(sc2, off);
      int yp = __shfl_up(sp2, off);
      if (lane >= off) { sc2 += yc; sp2 += yp; }
    }
    shA[lane] = sc2 - vc2;
    shB[lane] = sp2 - vp2;
  }
  __syncthreads();
  int ec = shA[wid] + (ic - lc);
  int ep = shB[wid] + (ip - lp);
#pragma unroll
  for (int i = 0; i < IT; ++i) {
    int idx = base2 + i;
    if (idx < nb) { cumc[idx] = ec; pairoff[idx] = ep; }
    ec += cv[i];
    ep += cv[i] * (cv[i] - 1) / 2;
  }
  if (t == NTHR - 1) scalars[0] = ep;  // total P (plain store; next kernel sees it)
}

// K2: scatter + run length + block-local offsets; LAST-FINISHING block scans
//     blockpart -> blockoff. Also resets zf for the next (graph-replayed) launch.
__global__ __launch_bounds__(NTHR) void k_scatter(
    const int* __restrict__ pv,
    const int* __restrict__ cumc,
    const int* __restrict__ counts,
    int* __restrict__ scalars,
    int* __restrict__ zf,
    int* __restrict__ fill,
    int* __restrict__ sorted,
    int* __restrict__ Oarr,
    int* __restrict__ blockpart,
    int* __restrict__ blockoff,
    int n) {
  __shared__ int shA[4];
  __shared__ int isLast;
  int t = threadIdx.x;
  int lane = t & 63, wid = t >> 6;
  int a = blockIdx.x * NTHR + t;
  if (blockIdx.x == 0 && t < ZBLK)
    __hip_atomic_store(&zf[t], 0, __ATOMIC_RELAXED, __HIP_MEMORY_SCOPE_AGENT);
  int g0 = scalars[8], g1 = scalars[9], g2 = scalars[10], g12 = scalars[11];
  int S = 0;
  if (a < n) {
    int p = pv[a];
    int v0 = p >> 20, v1 = (p >> 10) & 1023, v2 = p & 1023;
    int b = v0 * g12 + v1 * g1 + v2;
    int pos = cumc[b] + atomicAdd(&fill[b], 1);
    sorted[pos] = a;
#pragma unroll
    for (int m = 0; m < 7; ++m) {
      int dx = ((m >> 2) & 1) ? 0 : -1;
      int dy = ((m >> 1) & 1) ? 0 : -1;
      int dz = (m & 1) ? 0 : -1;
      int nx = v0 + dx; if (nx < 0) nx += g0;
      int ny = v1 + dy; if (ny < 0) ny += g1;
      int nz = v2 + dz; if (nz < 0) nz += g2;
      S += counts[nx * g12 + ny * g1 + nz];
    }
  }
  int iv = S;
  for (int off = 1; off < 64; off <<= 1) {
    int y = __shfl_up(iv, off);
    if (lane >= off) iv += y;
  }
  if (lane == 63) shA[wid] = iv;
  __syncthreads();
  if (wid == 0 && lane < 4) {
    int v2 = shA[lane], s2 = v2;
    for (int off = 1; off < 4; off <<= 1) {
      int y = __shfl_up(s2, off);
      if (lane >= off) s2 += y;
    }
    shA[lane] = s2 - v2;
    if (lane == 3) {
      // agent-scope relaxed atomic store: coherently visible to last block's loads
      __hip_atomic_store(&blockpart[blockIdx.x], s2, __ATOMIC_RELAXED,
                         __HIP_MEMORY_SCOPE_AGENT);
    }
  }
  __syncthreads();
  if (a < n) Oarr[a] = shA[wid] + (iv - S);

  // last-finishing-block detection (syncthreads drained vmcnt incl. the atomic store)
  __syncthreads();
  if (t == 0) {
    int old = __hip_atomic_fetch_add(&scalars[14], 1, __ATOMIC_RELAXED,
                                     __HIP_MEMORY_SCOPE_AGENT);
    isLast = (old == (int)gridDim.x - 1) ? 1 : 0;
  }
  __syncthreads();
  if (!isLast) return;

  int nblocks = gridDim.x;
  const int IT = 2;  // 256 x 2 = 512 >= nblocks
  int base2 = t * IT;
  int cv[IT];
  int ls = 0;
#pragma unroll
  for (int i = 0; i < IT; ++i) {
    int idx = base2 + i;
    int v = (idx < nblocks)
        ? __hip_atomic_load(&blockpart[idx], __ATOMIC_RELAXED, __HIP_MEMORY_SCOPE_AGENT)
        : 0;
    cv[i] = v;
    ls += v;
  }
  int il = ls;
  for (int off = 1; off < 64; off <<= 1) {
    int y = __shfl_up(il, off);
    if (lane >= off) il += y;
  }
  if (lane == 63) shA[wid] = il;
  __syncthreads();
  if (wid == 0 && lane < 4) {
    int v2 = shA[lane], s2 = v2;
    for (int off = 1; off < 4; off <<= 1) {
      int y = __shfl_up(s2, off);
      if (lane >= off) s2 += y;
    }
    shA[lane] = s2 - v2;
  }
  __syncthreads();
  int e = shA[wid] + (il - ls);
#pragma unroll
  for (int i = 0; i < IT; ++i) {
    int idx = base2 + i;
    if (idx < nblocks) blockoff[idx] = e;  // plain store; read next kernel
    e += cv[i];
  }
}

// K3: merged grid. Blocks [0,2048): per-bucket sort/perm/pairs. Blocks [2048,..): emit16.
__global__ __launch_bounds__(NTHR) void k_sortemit(
    const int* __restrict__ counts,
    const int* __restrict__ cumc,
    const int* __restrict__ pairoff,
    const int* __restrict__ scalars,
    int* __restrict__ sorted,
    const int* __restrict__ pv,
    const int* __restrict__ Oarr,
    const int* __restrict__ blockoff,
    float* __restrict__ out_im,
    float* __restrict__ out_at,
    float* __restrict__ out,
    int n) {
  int t = threadIdx.x;
  int lane = t & 63, wid = t >> 6;

  if (blockIdx.x < 2048) {
    int b = blockIdx.x * 4 + wid;
    int nb = scalars[12];
    if (b >= nb) return;
    int c = counts[b];
    if (c == 0) return;
    int s = cumc[b];
    if (c == 1) {
      if (lane == 0) {
        int aa = sorted[s];
        out_im[s] = (float)aa;
        out_at[aa] = (float)s;
      }
      return;
    }
    if (c <= 64) {
      int val = (lane < c) ? sorted[s + lane] : 0x7fffffff;
      int rank = 0;
      for (int j = 0; j < c; ++j) {
        int other = __shfl(val, j);
        rank += (other < val) ? 1 : 0;
      }
      if (lane < c) {
        sorted[s + rank] = val;
        out_im[s + rank] = (float)val;
        out_at[val] = (float)(s + rank);
      }
    } else if (lane == 0) {
      for (int i = 1; i < c; ++i) {
        int key = sorted[s + i];
        int j = i - 1;
        while (j >= 0 && sorted[s + j] > key) {
          sorted[s + j + 1] = sorted[s + j];
          --j;
        }
        sorted[s + j + 1] = key;
      }
      for (int i = 0; i < c; ++i) {
        int aa = sorted[s + i];
        out_im[s + i] = (float)aa;
        out_at[aa] = (float)(s + i);
      }
    }
    int off = pairoff[b];
    int P = scalars[0];
    int np = c * (c - 1) / 2;
    for (int k = lane; k < np; k += 64) {
      int l = (int)((1.0f + sqrtf(1.0f + 8.0f * (float)k)) * 0.5f);
      while (l * (l - 1) / 2 > k) --l;
      while ((l + 1) * l / 2 <= k) ++l;
      int u = k - l * (l - 1) / 2;
      out[off + k] = (float)(s + u);
      out[P + off + k] = (float)(s + l);
    }
    return;
  }

  // emit: 16 lanes per atom, 16 atoms per block
  int a = (blockIdx.x - 2048) * 16 + (t >> 4);
  int l16 = t & 15;
  if (a >= n) return;
  int g0 = scalars[8], g1 = scalars[9], g2 = scalars[10], g12 = scalars[11];
  int p = pv[a];
  int v0 = p >> 20, v1 = (p >> 10) & 1023, v2 = p & 1023;
  int segs[8];
  int cums[7];
  segs[0] = 0;
#pragma unroll
  for (int m = 0; m < 7; ++m) {
    int dx = ((m >> 2) & 1) ? 0 : -1;
    int dy = ((m >> 1) & 1) ? 0 : -1;
    int dz = (m & 1) ? 0 : -1;
    int nx = v0 + dx; if (nx < 0) nx += g0;
    int ny = v1 + dy; if (ny < 0) ny += g1;
    int nz = v2 + dz; if (nz < 0) nz += g2;
    int nb_ = nx * g12 + ny * g1 + nz;
    cums[m] = cumc[nb_];
    segs[m + 1] = segs[m] + counts[nb_];
  }
  int S = segs[7];
  long base = 2L * (long)scalars[0] + (long)blockoff[a >> 8] + (long)Oarr[a];
  for (int q = l16; q < S; q += 16) {
    int v = cums[0] + q;
#pragma unroll
    for (int m = 1; m < 7; ++m) {
      if (q >= segs[m]) v = cums[m] + (q - segs[m]);
    }
    out[base + q] = (float)v;
  }
}

extern "C" void kernel_launch(void* const* d_in, const int* in_sizes, int n_in,
                              void* d_out, int out_size, void* d_ws, size_t ws_size,
                              hipStream_t stream) {
  const float* coord = (const float*)d_in[0];
  const float* cell = (const float*)d_in[1];
  float* out = (float*)d_out;
  int n = in_sizes[0] / 3;

  int* W = (int*)d_ws;
  int* counts = W;                         // NB_MAX
  int* fill = W + NB_MAX;                  // NB_MAX
  int* scalars = W + 2 * NB_MAX;           // 16
  int* zf = scalars + 16;                  // 32
  int* cumc = zf + 32;                     // NB_MAX
  int* pairoff = cumc + NB_MAX;            // NB_MAX
  int* pv = pairoff + NB_MAX;              // n
  int* sorted = pv + n;                    // n
  int* Oarr = sorted + n;                  // n
  int* blockpart = Oarr + n;               // 1024
  int* blockoff = blockpart + 1024;        // 1024

  // output chunk bases known on host: out = [2P | L | 3n | n | n]
  float* out_frac = out + (out_size - 5 * n);
  float* out_im = out + (out_size - 2 * n);
  float* out_at = out + (out_size - n);

  int nblocks = (n + NTHR - 1) / NTHR;     // 391
  int eblocks = (n + 15) / 16;             // emit blocks (16 atoms each)

  // no memset dispatch: K1 self-zeroes counts/fill/scalars; everything else is
  // write-before-read each launch (poison-safe). K2 resets zf for graph replay.

  k_count<<<nblocks, NTHR, 0, stream>>>(coord, cell, out_frac, pv, counts, fill,
                                        scalars, zf, cumc, pairoff, n);
  k_scatter<<<nblocks, NTHR, 0, stream>>>(pv, cumc, counts, scalars, zf, fill,
                                          sorted, Oarr, blockpart, blockoff, n);
  k_sortemit<<<2048 + eblocks, NTHR, 0, stream>>>(counts, cumc, pairoff, scalars,
                                                  sorted, pv, Oarr, blockoff,
                                                  out_im, out_at, out, n);
}